// Round 1
// baseline (1521.785 us; speedup 1.0000x reference)
//
#include <hip/hip_runtime.h>
#include <hip/hip_bf16.h>
#include <stdint.h>

// Problem dims (fixed by reference)
#define BB 4096
#define D0 2048
#define D1 8192
#define D2 2048
#define WC 8

typedef __attribute__((ext_vector_type(8))) short bf16x8;
typedef __attribute__((ext_vector_type(4))) float f32x4;

__device__ __forceinline__ unsigned short f2bf(float f) {
    union { float f; unsigned int u; } v; v.f = f;
    unsigned int u = v.u;
    unsigned int r = u + 0x7FFFu + ((u >> 16) & 1u);  // RNE
    return (unsigned short)(r >> 16);
}

__device__ __forceinline__ void gl2lds16(const void* g, void* l) {
    __builtin_amdgcn_global_load_lds(
        (const __attribute__((address_space(1))) unsigned int*)g,
        (__attribute__((address_space(3))) unsigned int*)l,
        16, 0, 0);
}

// ---------------------------------------------------------------------------
// Cast x fp32 -> bf16, vectorized (float4 in, 8B out)
// ---------------------------------------------------------------------------
__global__ __launch_bounds__(256) void cast_f32_bf16_k(
    const float4* __restrict__ x, uint2* __restrict__ y, int n4)
{
    int t = blockIdx.x * blockDim.x + threadIdx.x;
    if (t < n4) {
        float4 v = x[t];
        uint2 o;
        o.x = (unsigned)f2bf(v.x) | ((unsigned)f2bf(v.y) << 16);
        o.y = (unsigned)f2bf(v.z) | ((unsigned)f2bf(v.w) << 16);
        y[t] = o;
    }
}

// ---------------------------------------------------------------------------
// Gather-select weights[i,o,idx[i,o]] -> bf16, store TRANSPOSED [Dout, Din].
// 64x64 tile per block, LDS transpose (row stride 66 elem = 33 dwords -> no
// bank conflicts on the transposed read). Reads coalesced along o, writes
// coalesced along i.
// ---------------------------------------------------------------------------
__global__ __launch_bounds__(256) void pack_select_T(
    const float* __restrict__ w, const int* __restrict__ idx,
    unsigned short* __restrict__ outT, int Din, int Dout)
{
    __shared__ unsigned short tile[64][66];
    const int i0 = blockIdx.y * 64;
    const int o0 = blockIdx.x * 64;
    const int tid = threadIdx.x;

    #pragma unroll
    for (int e = 0; e < 16; ++e) {
        int el = e * 256 + tid;
        int r = el >> 6, c = el & 63;           // r: i-local, c: o-local
        long g = (long)(i0 + r) * Dout + (o0 + c);
        int id = idx[g];
        float v = w[g * (long)WC + id];
        tile[r][c] = f2bf(v);
    }
    __syncthreads();
    #pragma unroll
    for (int e = 0; e < 16; ++e) {
        int el = e * 256 + tid;
        int r2 = el >> 6, c2 = el & 63;         // r2: o-local, c2: i-local
        outT[(long)(o0 + r2) * Din + (i0 + c2)] = tile[c2][r2];
    }
}

// ---------------------------------------------------------------------------
// C[M,N] = relu(A[M,K] @ Bt[N,K]^T + bias[N])
// bf16 inputs, fp32 accumulate. 128x128 tile, BK=32, 256 threads = 4 waves,
// each wave 64x64 (4x4 grid of 16x16x32 MFMA). global_load_lds width=16
// staging (LDS layout contiguous in chunk order: lane-uniform base + lane*16).
// ---------------------------------------------------------------------------
template <bool OUT_F32>
__global__ __launch_bounds__(256) void gemm_bt_bias_relu(
    const unsigned short* __restrict__ A,
    const unsigned short* __restrict__ Bt,
    const float* __restrict__ bias,
    void* __restrict__ Cout,
    int M, int N, int K)
{
    __shared__ unsigned short sA[128 * 32];
    __shared__ unsigned short sB[128 * 32];

    const int tid  = threadIdx.x;
    const int lane = tid & 63;
    const int wave = tid >> 6;
    const int wm   = (wave >> 1) * 64;
    const int wn   = (wave & 1) * 64;
    const int l15  = lane & 15;
    const int quad = lane >> 4;
    const long bm  = (long)blockIdx.y * 128;
    const long bn  = (long)blockIdx.x * 128;

    f32x4 acc[4][4] = {};

    // chunk c in [0,512): tile row = c>>2, 16B segment = c&3 ; lds off = c*16B
    const int c0 = tid, c1 = tid + 256;
    const unsigned short* a0 = A  + (bm + (c0 >> 2)) * K + (c0 & 3) * 8;
    const unsigned short* a1 = A  + (bm + (c1 >> 2)) * K + (c1 & 3) * 8;
    const unsigned short* b0 = Bt + (bn + (c0 >> 2)) * K + (c0 & 3) * 8;
    const unsigned short* b1 = Bt + (bn + (c1 >> 2)) * K + (c1 & 3) * 8;

    for (int bk = 0; bk < K; bk += 32) {
        gl2lds16(a0 + bk, &sA[c0 * 8]);
        gl2lds16(a1 + bk, &sA[c1 * 8]);
        gl2lds16(b0 + bk, &sB[c0 * 8]);
        gl2lds16(b1 + bk, &sB[c1 * 8]);
        __syncthreads();

        bf16x8 af[4], bfr[4];
        #pragma unroll
        for (int i = 0; i < 4; ++i) {
            af[i]  = *(const bf16x8*)&sA[(wm + i * 16 + l15) * 32 + quad * 8];
            bfr[i] = *(const bf16x8*)&sB[(wn + i * 16 + l15) * 32 + quad * 8];
        }
        #pragma unroll
        for (int mi = 0; mi < 4; ++mi)
            #pragma unroll
            for (int ni = 0; ni < 4; ++ni)
                acc[mi][ni] = __builtin_amdgcn_mfma_f32_16x16x32_bf16(
                    af[mi], bfr[ni], acc[mi][ni], 0, 0, 0);
        __syncthreads();
    }

    // Epilogue: C/D layout col=lane&15, row=(lane>>4)*4+reg (m89-verified)
    float bv[4];
    #pragma unroll
    for (int ni = 0; ni < 4; ++ni) bv[ni] = bias[bn + wn + ni * 16 + l15];

    #pragma unroll
    for (int mi = 0; mi < 4; ++mi) {
        #pragma unroll
        for (int ni = 0; ni < 4; ++ni) {
            const long col = bn + wn + ni * 16 + l15;
            #pragma unroll
            for (int r = 0; r < 4; ++r) {
                const long row = bm + wm + mi * 16 + quad * 4 + r;
                float v = acc[mi][ni][r] + bv[ni];
                v = v > 0.f ? v : 0.f;
                if (OUT_F32) ((float*)Cout)[row * (long)N + col] = v;
                else ((unsigned short*)Cout)[row * (long)N + col] = f2bf(v);
            }
        }
    }
}

// ---------------------------------------------------------------------------
// Launch. Workspace layout (peak 112 MiB):
//   xb  @ 0       (16 MiB)  x cast to bf16          [4096,2048]
//   w1T @ 16 MiB  (32 MiB)  selected W1^T bf16      [8192,2048]
//   h   @ 48 MiB  (64 MiB)  layer-1 output bf16     [4096,8192]
//   w2T @ 0       (32 MiB)  selected W2^T bf16      [2048,8192] (reuses xb/w1T
//                           region — pack2 runs AFTER gemm1)
// ---------------------------------------------------------------------------
extern "C" void kernel_launch(void* const* d_in, const int* in_sizes, int n_in,
                              void* d_out, int out_size, void* d_ws, size_t ws_size,
                              hipStream_t stream)
{
    const float* x  = (const float*)d_in[0];
    const float* w1 = (const float*)d_in[1];
    const float* b1 = (const float*)d_in[2];
    const int*   i1 = (const int*)d_in[3];
    const float* w2 = (const float*)d_in[4];
    const float* b2 = (const float*)d_in[5];
    const int*   i2 = (const int*)d_in[6];
    float* out = (float*)d_out;

    char* ws = (char*)d_ws;
    unsigned short* xb  = (unsigned short*)(ws);
    unsigned short* w1T = (unsigned short*)(ws + (16ull << 20));
    unsigned short* h   = (unsigned short*)(ws + (48ull << 20));
    unsigned short* w2T = (unsigned short*)(ws);  // overlays xb/w1T after gemm1

    // 1. cast x -> bf16
    {
        int n4 = (BB * D0) / 4;
        cast_f32_bf16_k<<<n4 / 256, 256, 0, stream>>>((const float4*)x, (uint2*)xb, n4);
    }
    // 2. pack layer-1 weights (select + transpose + bf16)
    pack_select_T<<<dim3(D1 / 64, D0 / 64), 256, 0, stream>>>(w1, i1, w1T, D0, D1);
    // 3. GEMM1: h = relu(xb @ w1T^T + b1), bf16 out
    gemm_bt_bias_relu<false><<<dim3(D1 / 128, BB / 128), 256, 0, stream>>>(
        xb, w1T, b1, (void*)h, BB, D1, D0);
    // 4. pack layer-2 weights
    pack_select_T<<<dim3(D2 / 64, D1 / 64), 256, 0, stream>>>(w2, i2, w2T, D1, D2);
    // 5. GEMM2: out = relu(h @ w2T^T + b2), fp32 out
    gemm_bt_bias_relu<true><<<dim3(D2 / 128, BB / 128), 256, 0, stream>>>(
        h, w2T, b2, (void*)out, BB, D2, D1);
}